// Round 8
// baseline (2233.504 us; speedup 1.0000x reference)
//
#include <hip/hip_runtime.h>
#include <math.h>

#define Bsz 8
#define Dd  128
#define Tt  4096
#define Kk  1024
#define NQ  8
#define BT  (Bsz*Tt)        // 32768 points
#define MT  128             // points per block (8 waves; 2 halves x 32 pts)
#define NTHR 512
#define WV  8

typedef float f32x4 __attribute__((ext_vector_type(4)));
typedef short short8 __attribute__((ext_vector_type(8)));

__device__ __forceinline__ unsigned short f2bf(float x) {   // RNE f32->bf16
    unsigned u = __float_as_uint(x);
    u += 0x7FFF + ((u >> 16) & 1);
    return (unsigned short)(u >> 16);
}
__device__ __forceinline__ float bf2f(unsigned short h) {
    return __uint_as_float(((unsigned)h) << 16);
}

// ---------------------------------------------------------------------------
// init: transpose x (B,D,T) -> resid (B,T,D)
// ---------------------------------------------------------------------------
__global__ void k_init(const float* __restrict__ x,
                       float* __restrict__ resid) {
    __shared__ float tile[32][33];
    int b  = blockIdx.z;
    int t0 = blockIdx.x * 32, d0 = blockIdx.y * 32;
    int tx = threadIdx.x, ty = threadIdx.y;   // 32 x 8
    #pragma unroll
    for (int k = 0; k < 4; k++) {
        int d = d0 + ty + k * 8;
        tile[ty + k * 8][tx] = x[((size_t)(b * Dd + d)) * Tt + t0 + tx];
    }
    __syncthreads();
    #pragma unroll
    for (int k = 0; k < 4; k++) {
        int t = t0 + ty + k * 8;
        resid[((size_t)(b * Tt + t)) * Dd + d0 + tx] = tile[tx][ty + k * 8];
    }
}

// ---------------------------------------------------------------------------
// k_prep: split codebook into hi/lo bf16, pre-swizzled into MFMA B-fragment
// order. B-frag (16x16x32 bf16): lane holds col n=lane&15, k=quad*8+j.
// Layout per (q, tile): 8192 B = [ch kc0..3 (1KB each) | cl kc0..3].
// ---------------------------------------------------------------------------
__global__ void k_prep(const float* __restrict__ cb, char* __restrict__ bswz) {
    int ln = threadIdx.x;                 // 64
    int kc = blockIdx.x & 3;
    int t  = (blockIdx.x >> 2) & 63;
    int q  = blockIdx.x >> 8;
    int code = t * 16 + (ln & 15);
    int d0   = kc * 32 + (ln >> 4) * 8;
    const float* src = cb + ((size_t)(q * Kk + code)) * Dd + d0;
    float v[8];
    *(float4*)&v[0] = *(const float4*)src;
    *(float4*)&v[4] = *(const float4*)(src + 4);
    short8 h, l;
    #pragma unroll
    for (int j = 0; j < 8; j++) {
        unsigned short hu = f2bf(v[j]);
        h[j] = (short)hu;
        l[j] = (short)f2bf(v[j] - bf2f(hu));   // exact remainder, then RNE
    }
    char* base = bswz + ((size_t)(q * 64 + t)) * 8192;
    *(short8*)(base + kc * 1024 + ln * 16) = h;
    *(short8*)(base + 4096 + kc * 1024 + ln * 16) = l;
}

// ---------------------------------------------------------------------------
// c2[q][k] = sum_d cb[q][k][d]^2 (exact f32) ; zero commit accumulators.
// (No atomicMax / no memset dependency — cmax is reduced in-kernel.)
// ---------------------------------------------------------------------------
__global__ void k_c2(const float* __restrict__ cb,
                     float* __restrict__ c2,
                     double* __restrict__ commits) {
    int row  = blockIdx.x * 4 + (threadIdx.x >> 6);
    int lane = threadIdx.x & 63;
    const float* p = cb + (size_t)row * Dd;
    float a = p[lane], b = p[lane + 64];
    float s = a * a + b * b;
    #pragma unroll
    for (int off = 32; off; off >>= 1) s += __shfl_down(s, off);
    if (lane == 0) c2[row] = s;
    if (blockIdx.x == 0 && threadIdx.x < NQ) commits[threadIdx.x] = 0.0;
}

// exact f32 chain, d ascending, rlds XOR-swizzled row — numeric order
// identical to the validated version (same fma sequence).
__device__ __forceinline__ float exact_score_sw(const float* __restrict__ rldsb,
                                                int p,
                                                const float* __restrict__ crow,
                                                float c2v) {
    const f32x4* r4 = (const f32x4*)rldsb;
    const f32x4* c4 = (const f32x4*)crow;
    int rb = p * 32, sw = p & 7;
    float a = 0.0f;
    #pragma unroll
    for (int d4 = 0; d4 < 32; d4++) {
        f32x4 r = r4[rb + (d4 ^ sw)];
        f32x4 c = c4[d4];
        a = fmaf(r[0], c[0], a); a = fmaf(r[1], c[1], a);
        a = fmaf(r[2], c[2], a); a = fmaf(r[3], c[3], a);
    }
    return fmaf(-2.0f, a, c2v);
}

// ---------------------------------------------------------------------------
// Fused persistent RVQ. 256 blocks x 512 thr (8 waves). Waves 0-3 screen
// codes [0,512), waves 4-7 [512,1024) (r5-validated split); each wave owns
// 32 points = 2 A-sets (rows wg*32+m / +16, wg=w&3). The measured wall is
// LDS B-read throughput (0.75 of 1.02 cyc/score at 16 pts/wave); 32
// pts/wave amortizes each 8 KB tile read over 2x points -> 0.375.
// Screening: A-HI only x B-(hi+lo) (r5-validated numerics, 8 MFMA/tile).
// Top-3 PACKED (code idx in low 10 mantissa bits; min/med3 updates).
// Certification exact via the r5-validated per-point window:
//   err <= 2^-8*1.005*||r||*cmax + accum ; pack <= 2^(E-13);
//   win = 0.016*||r||*cmax + 0.06 + 2^E/4096 >= 2*(err+pack), 2x slack.
// Contested -> exact f32 rescore w/ index tie-break; >=3 in window ->
// wave-parallel exact fallback scan (8 points concurrently). Codes exact.
// cmax reduced in-kernel from c2s (drops memset/atomicMax overhead).
// ---------------------------------------------------------------------------
__global__ __launch_bounds__(NTHR, 2) void k_rvq_fused(
        float* __restrict__ resid,         // in: initial (B,T,D); out: final
        const float* __restrict__ cb,      // (NQ,K,D) f32
        const char*  __restrict__ bswz,    // (NQ*64 tiles) * 8192 B
        const float* __restrict__ c2g,     // (NQ,K) exact f32
        float* __restrict__ codes_f,       // (NQ,BT)
        double* __restrict__ commits) {    // (NQ)
    __shared__ float rlds[MT * Dd];        // 64 KB, XOR-swizzled f32x4 rows
    __shared__ float c2s[Kk];              // 4 KB
    __shared__ f32x4 bbuf[2][2][512];      // 32 KB [par][half][slice]
    __shared__ float winp[MT];             // per-point rigorous window
    __shared__ float wmax[WV];             // per-wave c2 max partials
    __shared__ float fA1[MT], fA2[MT], fA3[MT];   // packed triples half 0
    __shared__ float fB1[MT], fB2[MT], fB3[MT];   // packed triples half 1
    __shared__ int   sidxs[MT];
    __shared__ int   nfall, flist[MT];
    __shared__ float csum[WV];

    const int tid  = threadIdx.x;
    const int w    = tid >> 6, ln = tid & 63;
    const int quad = ln >> 4,  m  = ln & 15;
    const int wg   = w & 3,    half = w >> 2;
    const int base = blockIdx.x * MT;
    const int prow0 = wg * 32 + m;         // set-0 row (0..127)
    const int prow1 = wg * 32 + 16 + m;    // set-1 row

    f32x4* r4 = (f32x4*)rlds;

    // block residual -> swizzled LDS (coalesced, once)
    {
        const f32x4* src = (const f32x4*)(resid + (size_t)base * Dd);
        #pragma unroll
        for (int i = 0; i < (MT * Dd / 4) / NTHR; i++) {    // 8 iters
            int idx = tid + i * NTHR;
            int row = idx >> 5, c4 = idx & 31;
            r4[row * 32 + (c4 ^ (row & 7))] = src[idx];
        }
    }
    // prologue: stage pair 0 of stage 0 (tiles 0 and 32)
    {
        const f32x4* B0 = (const f32x4*)bswz;
        bbuf[0][0][tid] = B0[tid];
        bbuf[0][1][tid] = B0[tid + 32 * 512];
    }
    int par = 0;
    __syncthreads();

    #pragma unroll 1
    for (int q = 0; q < NQ; q++) {
        const float* cbq = cb + (size_t)q * Kk * Dd;
        c2s[tid]        = c2g[q * Kk + tid];
        c2s[tid + NTHR] = c2g[q * Kk + tid + NTHR];
        if (tid == 0) nfall = 0;
        __syncthreads();   // c2s ready

        // in-kernel cmax = max_k ||c_k||^2 (block reduce over c2s)
        float lm = fmaxf(c2s[tid], c2s[tid + NTHR]);
        #pragma unroll
        for (int off = 32; off; off >>= 1) lm = fmaxf(lm, __shfl_xor(lm, off));
        if (ln == 0) wmax[w] = lm;
        __syncthreads();
        float cm2 = wmax[0];
        #pragma unroll
        for (int w2 = 1; w2 < WV; w2++) cm2 = fmaxf(cm2, wmax[w2]);
        float cmaxq = sqrtf(cm2);

        // A-fragments (hi bf16 only), 2 sets; exact ||r||^2 per set
        short8 Ah0[4], Ah1[4];
        float r2p0 = 0.0f, r2p1 = 0.0f;
        #pragma unroll
        for (int kc = 0; kc < 4; kc++) {
            int c4a = kc * 8 + quad * 2;
            float v[8];
            short8 h;
            *(f32x4*)&v[0] = r4[prow0 * 32 + (c4a ^ (prow0 & 7))];
            *(f32x4*)&v[4] = r4[prow0 * 32 + ((c4a + 1) ^ (prow0 & 7))];
            #pragma unroll
            for (int j = 0; j < 8; j++) {
                h[j] = (short)f2bf(v[j]);
                r2p0 = fmaf(v[j], v[j], r2p0);
            }
            Ah0[kc] = h;
            *(f32x4*)&v[0] = r4[prow1 * 32 + (c4a ^ (prow1 & 7))];
            *(f32x4*)&v[4] = r4[prow1 * 32 + ((c4a + 1) ^ (prow1 & 7))];
            #pragma unroll
            for (int j = 0; j < 8; j++) {
                h[j] = (short)f2bf(v[j]);
                r2p1 = fmaf(v[j], v[j], r2p1);
            }
            Ah1[kc] = h;
        }
        r2p0 += __shfl_xor(r2p0, 16); r2p0 += __shfl_xor(r2p0, 32);
        r2p1 += __shfl_xor(r2p1, 16); r2p1 += __shfl_xor(r2p1, 32);
        {   // rigorous per-point windows (r5-validated formula)
            float R0 = sqrtf(r2p0), R1 = sqrtf(r2p1);
            float sb0 = fmaf(2.0f * R0, cmaxq, cmaxq * cmaxq);
            float sb1 = fmaf(2.0f * R1, cmaxq, cmaxq * cmaxq);
            float p20 = exp2f(ceilf(log2f(fmaxf(sb0, 2.0f))));
            float p21 = exp2f(ceilf(log2f(fmaxf(sb1, 2.0f))));
            float w0 = fmaf(0.016f * R0, cmaxq, 0.06f) + p20 * (1.0f/4096.0f);
            float w1 = fmaf(0.016f * R1, cmaxq, 0.06f) + p21 * (1.0f/4096.0f);
            if (quad == 0) { winp[prow0] = w0; winp[prow1] = w1; }
        }

        // packed top-3 state, 2 sets x 4 point-slots
        float b1a[4], b2a[4], b3a[4], b1b[4], b2b[4], b3b[4];
        #pragma unroll
        for (int j = 0; j < 4; j++) {
            b1a[j] = INFINITY; b2a[j] = INFINITY; b3a[j] = INFINITY;
            b1b[j] = INFINITY; b2b[j] = INFINITY; b3b[j] = INFINITY;
        }
        __syncthreads();   // winp ready; bbuf[par] holds this stage's pair 0

        #pragma unroll 1
        for (int s = 0; s < 32; s++) {
            const int pidx = q * 32 + s + 1;       // next pair index
            const bool hs = (pidx < NQ * 32);
            f32x4 stg0, stg1;
            if (hs) {
                int nq = pidx >> 5, ns = pidx & 31;
                const f32x4* Bn0 =
                    (const f32x4*)(bswz + ((size_t)(nq * 64 + ns)) * 8192);
                const f32x4* Bn1 =
                    (const f32x4*)(bswz + ((size_t)(nq * 64 + 32 + ns)) * 8192);
                stg0 = Bn0[tid];
                stg1 = Bn1[tid];
            }
            const char* bb = (const char*)&bbuf[par][half][0];
            f32x4 a01A = {0.f,0.f,0.f,0.f}, a23A = {0.f,0.f,0.f,0.f};
            f32x4 a01B = {0.f,0.f,0.f,0.f}, a23B = {0.f,0.f,0.f,0.f};
            __builtin_amdgcn_s_setprio(1);
            #pragma unroll
            for (int kc = 0; kc < 4; kc++) {
                short8 ch = *(const short8*)(bb + kc * 1024 + ln * 16);
                short8 cl = *(const short8*)(bb + 4096 + kc * 1024 + ln * 16);
                if (kc < 2) {
                    a01A = __builtin_amdgcn_mfma_f32_16x16x32_bf16(Ah0[kc], ch, a01A, 0, 0, 0);
                    a01A = __builtin_amdgcn_mfma_f32_16x16x32_bf16(Ah0[kc], cl, a01A, 0, 0, 0);
                    a01B = __builtin_amdgcn_mfma_f32_16x16x32_bf16(Ah1[kc], ch, a01B, 0, 0, 0);
                    a01B = __builtin_amdgcn_mfma_f32_16x16x32_bf16(Ah1[kc], cl, a01B, 0, 0, 0);
                } else {
                    a23A = __builtin_amdgcn_mfma_f32_16x16x32_bf16(Ah0[kc], ch, a23A, 0, 0, 0);
                    a23A = __builtin_amdgcn_mfma_f32_16x16x32_bf16(Ah0[kc], cl, a23A, 0, 0, 0);
                    a23B = __builtin_amdgcn_mfma_f32_16x16x32_bf16(Ah1[kc], ch, a23B, 0, 0, 0);
                    a23B = __builtin_amdgcn_mfma_f32_16x16x32_bf16(Ah1[kc], cl, a23B, 0, 0, 0);
                }
            }
            __builtin_amdgcn_s_setprio(0);
            const int codei = half * 512 + s * 16 + m;   // 0..1023 ascending
            float c2v = c2s[codei];
            const unsigned codeu = (unsigned)codei;
            #pragma unroll
            for (int j = 0; j < 4; j++) {
                float sA = fmaf(-2.0f, a01A[j] + a23A[j], c2v);
                float pA = __uint_as_float(
                    (__float_as_uint(sA) & 0xFFFFFC00u) | codeu);
                b3a[j] = __builtin_amdgcn_fmed3f(pA, b2a[j], b3a[j]);
                b2a[j] = __builtin_amdgcn_fmed3f(pA, b1a[j], b2a[j]);
                b1a[j] = fminf(b1a[j], pA);
                float sB = fmaf(-2.0f, a01B[j] + a23B[j], c2v);
                float pB = __uint_as_float(
                    (__float_as_uint(sB) & 0xFFFFFC00u) | codeu);
                b3b[j] = __builtin_amdgcn_fmed3f(pB, b2b[j], b3b[j]);
                b2b[j] = __builtin_amdgcn_fmed3f(pB, b1b[j], b2b[j]);
                b1b[j] = fminf(b1b[j], pB);
            }
            if (hs) {
                bbuf[par ^ 1][0][tid] = stg0;
                bbuf[par ^ 1][1][tid] = stg1;
            }
            __syncthreads();
            par ^= 1;
        }

        // cross-lane merge of sorted packed triples over the 16 code-cols
        #pragma unroll
        for (int set = 0; set < 2; set++) {
            #pragma unroll
            for (int j = 0; j < 4; j++) {
                float v1 = set ? b1b[j] : b1a[j];
                float v2 = set ? b2b[j] : b2a[j];
                float v3 = set ? b3b[j] : b3a[j];
                #pragma unroll
                for (int off = 1; off < 16; off <<= 1) {
                    float w1 = __shfl_xor(v1, off);
                    float w2 = __shfl_xor(v2, off);
                    float w3 = __shfl_xor(v3, off);
                    bool aw = v1 < w1;
                    float x2 = aw ? v2 : w2, x3 = aw ? v3 : w3;
                    float z1 = aw ? w1 : v1, z2 = aw ? w2 : v2;
                    v1 = fminf(v1, w1);
                    bool s2 = x2 < z1;
                    v2 = fminf(x2, z1);
                    v3 = s2 ? fminf(x3, z1) : fminf(x2, z2);
                }
                if (m == 0) {
                    int p = wg * 32 + set * 16 + quad * 4 + j;
                    if (half == 0) { fA1[p] = v1; fA2[p] = v2; fA3[p] = v3; }
                    else           { fB1[p] = v1; fB2[p] = v2; fB3[p] = v3; }
                }
            }
        }
        __syncthreads();

        // decision: merge half-triples (r5-validated), window certification,
        // exact rescore of <=2 candidates (thread per point).
        if (tid < MT) {
            int p = tid;
            float vA1 = fA1[p], vA2 = fA2[p], vA3 = fA3[p];
            float vB1 = fB1[p], vB2 = fB2[p], vB3 = fB3[p];
            bool aw = vA1 < vB1;
            float x2 = aw ? vA2 : vB2, x3 = aw ? vA3 : vB3;
            float z1 = aw ? vB1 : vA1, z2 = aw ? vB2 : vA2;
            float v1 = fminf(vA1, vB1);
            bool s2 = x2 < z1;
            float v2 = fminf(x2, z1);
            float v3 = s2 ? fminf(x3, z1) : fminf(x2, z2);
            int a1 = (int)(__float_as_uint(v1) & 1023u);
            int a2 = (int)(__float_as_uint(v2) & 1023u);
            float win = winp[p];
            if (v3 <= v1 + win) {
                int sl = atomicAdd(&nfall, 1);     // >=3 in window
                flist[sl] = p;
            } else {
                int bk = a1;
                if (v2 <= v1 + win) {              // two candidates: rescore
                    float s1 = exact_score_sw(rlds, p, cbq + (size_t)a1 * Dd, c2s[a1]);
                    float s2e = exact_score_sw(rlds, p, cbq + (size_t)a2 * Dd, c2s[a2]);
                    if (s2e < s1 || (s2e == s1 && a2 < a1)) bk = a2;
                }
                sidxs[p] = bk;
                codes_f[(size_t)q * BT + base + p] = (float)bk;
            }
        }
        __syncthreads();

        // fallback: WAVE-parallel exact scan (8 points concurrently)
        {
            int nf = nfall;
            for (int fi0 = 0; fi0 < nf; fi0 += WV) {
                int fi = fi0 + w;
                if (fi < nf) {
                    int p = flist[fi];
                    float bv = INFINITY; int bk = 0;
                    #pragma unroll 4
                    for (int c = 0; c < 16; c++) {
                        int k = c * 64 + ln;       // ascending within lane
                        float sc = exact_score_sw(rlds, p,
                                                  cbq + (size_t)k * Dd, c2s[k]);
                        if (sc < bv || (sc == bv && k < bk)) { bv = sc; bk = k; }
                    }
                    #pragma unroll
                    for (int off = 32; off; off >>= 1) {
                        float v2 = __shfl_xor(bv, off);
                        int   k2 = __shfl_xor(bk, off);
                        if (v2 < bv || (v2 == bv && k2 < bk)) { bv = v2; bk = k2; }
                    }
                    if (ln == 0) {
                        sidxs[p] = bk;
                        codes_f[(size_t)q * BT + base + p] = (float)bk;
                    }
                }
            }
        }
        __syncthreads();

        // fused STE update (swizzled rlds): thread -> point tid>>2,
        // dims [(tid&3)*32, +32). Per-element op order bit-identical.
        {
            int p = tid >> 2;
            int rb = p * 32, sw = p & 7, cb4 = (tid & 3) * 8;
            const float* qrow = cbq + ((size_t)sidxs[p]) * Dd + (tid & 3) * 32;
            float cacc = 0.0f;
            #pragma unroll
            for (int hh = 0; hh < 8; hh++) {
                f32x4 r  = r4[rb + ((cb4 + hh) ^ sw)];
                f32x4 qv = *(const f32x4*)(qrow + hh * 4);
                float t1x = qv[0] - r[0], t1y = qv[1] - r[1];
                float t1z = qv[2] - r[2], t1w = qv[3] - r[3];  // q - residual
                float qsx = r[0] + t1x, qsy = r[1] + t1y;
                float qsz = r[2] + t1z, qsw = r[3] + t1w;      // straight-through
                f32x4 nr = { r[0] - qsx, r[1] - qsy, r[2] - qsz, r[3] - qsw };
                r4[rb + ((cb4 + hh) ^ sw)] = nr;
                cacc = fmaf(t1x, t1x, cacc); cacc = fmaf(t1y, t1y, cacc);
                cacc = fmaf(t1z, t1z, cacc); cacc = fmaf(t1w, t1w, cacc);
            }
            #pragma unroll
            for (int off = 32; off; off >>= 1) cacc += __shfl_down(cacc, off);
            if (ln == 0) csum[w] = cacc;
        }
        __syncthreads();
        if (tid == 0) {
            double sd = 0.0;
            #pragma unroll
            for (int w2 = 0; w2 < WV; w2++) sd += (double)csum[w2];
            atomicAdd(commits + q, sd);
        }
        __syncthreads();   // gates next stage's c2s overwrite + A-prep
    }

    // final residual back to global (coalesced, once)
    {
        f32x4* dst = (f32x4*)(resid + (size_t)base * Dd);
        #pragma unroll
        for (int i = 0; i < (MT * Dd / 4) / NTHR; i++) {
            int idx = tid + i * NTHR;
            int row = idx >> 5, c4 = idx & 31;
            dst[idx] = r4[row * 32 + (c4 ^ (row & 7))];
        }
    }
}

// ---------------------------------------------------------------------------
// final: out(B,D,T) = x - resid_final^T
// ---------------------------------------------------------------------------
__global__ void k_final(const float* __restrict__ x,
                        const float* __restrict__ resid,
                        float* __restrict__ outq) {
    __shared__ float tile[32][33];
    int b  = blockIdx.z;
    int t0 = blockIdx.x * 32, d0 = blockIdx.y * 32;
    int tx = threadIdx.x, ty = threadIdx.y;   // 32 x 8
    #pragma unroll
    for (int k = 0; k < 4; k++) {
        int t = t0 + ty + k * 8;
        tile[ty + k * 8][tx] = resid[((size_t)(b * Tt + t)) * Dd + d0 + tx];
    }
    __syncthreads();
    #pragma unroll
    for (int k = 0; k < 4; k++) {
        int d = d0 + ty + k * 8;
        size_t o = ((size_t)(b * Dd + d)) * Tt + t0 + tx;
        outq[o] = x[o] - tile[tx][ty + k * 8];
    }
}

// ---------------------------------------------------------------------------
// scalars: bw = n_q * log2(K) * frame_rate ; penalty = mean(commits)
// ---------------------------------------------------------------------------
__global__ void k_scalars(const double* __restrict__ commits,
                          const int* __restrict__ frame_rate,
                          float* __restrict__ outs) {
    if (threadIdx.x == 0 && blockIdx.x == 0) {
        double s = 0.0;
        #pragma unroll
        for (int q = 0; q < NQ; q++) s += commits[q];
        double per_elem = s / ((double)NQ * (double)BT * (double)Dd);
        outs[0] = (float)(NQ * 10.0 * (double)frame_rate[0]); // log2(1024)=10
        outs[1] = (float)per_elem;
    }
}

extern "C" void kernel_launch(void* const* d_in, const int* in_sizes, int n_in,
                              void* d_out, int out_size, void* d_ws, size_t ws_size,
                              hipStream_t stream) {
    const float* x  = (const float*)d_in[0];   // (B, D, T)
    const float* cb = (const float*)d_in[1];   // (NQ, K, D)
    const int*   fr = (const int*)d_in[2];     // frame_rate

    float* outq    = (float*)d_out;                       // (B,D,T) 4194304
    float* codes_f = outq + (size_t)Bsz * Dd * Tt;        // (NQ,B,T) 262144
    float* scal    = codes_f + (size_t)NQ * BT;           // bw, penalty

    char* ws = (char*)d_ws;
    float*    resid   = (float*)ws;                            // BT*D f32
    float*    c2      = resid + (size_t)BT * Dd;               // NQ*K f32
    double*   commits = (double*)(c2 + (size_t)NQ * Kk);       // NQ f64
    size_t    off     = (size_t)((char*)(commits + NQ) - ws);
    char*     bswz    = ws + ((off + 255) & ~(size_t)255);     // 256B aligned

    dim3 tb(32, 8, 1);
    k_init<<<dim3(Tt / 32, Dd / 32, Bsz), tb, 0, stream>>>(x, resid);
    k_prep<<<NQ * 256, 64, 0, stream>>>(cb, bswz);
    k_c2<<<NQ * Kk / 4, 256, 0, stream>>>(cb, c2, commits);

    k_rvq_fused<<<BT / MT, NTHR, 0, stream>>>(resid, cb, bswz, c2,
                                              codes_f, commits);

    k_final<<<dim3(Tt / 32, Dd / 32, Bsz), tb, 0, stream>>>(x, resid, outq);
    k_scalars<<<1, 64, 0, stream>>>(commits, fr, scal);
}

// Round 9
// 468.140 us; speedup vs baseline: 4.7710x; 4.7710x over previous
//
#include <hip/hip_runtime.h>
#include <math.h>

#define Bsz 8
#define Dd  128
#define Tt  4096
#define Kk  1024
#define NQ  8
#define BT  (Bsz*Tt)        // 32768 points
#define MT  128             // points per block (8 waves x 16)
#define NTHR 512
#define WV  8

typedef float f32x4 __attribute__((ext_vector_type(4)));
typedef short short8 __attribute__((ext_vector_type(8)));

__device__ __forceinline__ unsigned short f2bf(float x) {   // RNE f32->bf16
    unsigned u = __float_as_uint(x);
    u += 0x7FFF + ((u >> 16) & 1);
    return (unsigned short)(u >> 16);
}
__device__ __forceinline__ float bf2f(unsigned short h) {
    return __uint_as_float(((unsigned)h) << 16);
}

// async global->LDS, 16B per lane (r2-validated). LDS dest is wave-uniform;
// HW adds lane*16. Global src is per-lane.
__device__ __forceinline__ void gload_lds16(const void* g, void* l) {
    __builtin_amdgcn_global_load_lds(
        (const __attribute__((address_space(1))) unsigned int*)g,
        (__attribute__((address_space(3))) unsigned int*)l, 16, 0, 0);
}

// ---------------------------------------------------------------------------
// init: transpose x (B,D,T) -> resid (B,T,D)
// ---------------------------------------------------------------------------
__global__ void k_init(const float* __restrict__ x,
                       float* __restrict__ resid) {
    __shared__ float tile[32][33];
    int b  = blockIdx.z;
    int t0 = blockIdx.x * 32, d0 = blockIdx.y * 32;
    int tx = threadIdx.x, ty = threadIdx.y;   // 32 x 8
    #pragma unroll
    for (int k = 0; k < 4; k++) {
        int d = d0 + ty + k * 8;
        tile[ty + k * 8][tx] = x[((size_t)(b * Dd + d)) * Tt + t0 + tx];
    }
    __syncthreads();
    #pragma unroll
    for (int k = 0; k < 4; k++) {
        int t = t0 + ty + k * 8;
        resid[((size_t)(b * Tt + t)) * Dd + d0 + tx] = tile[tx][ty + k * 8];
    }
}

// ---------------------------------------------------------------------------
// k_prep: split codebook into hi/lo bf16, pre-swizzled into MFMA B-fragment
// order. B-frag (16x16x32 bf16): lane holds col n=lane&15, k=quad*8+j.
// Layout per (q, tile): 8192 B = [ch kc0..3 (1KB each) | cl kc0..3].
// ---------------------------------------------------------------------------
__global__ void k_prep(const float* __restrict__ cb, char* __restrict__ bswz) {
    int ln = threadIdx.x;                 // 64
    int kc = blockIdx.x & 3;
    int t  = (blockIdx.x >> 2) & 63;
    int q  = blockIdx.x >> 8;
    int code = t * 16 + (ln & 15);
    int d0   = kc * 32 + (ln >> 4) * 8;
    const float* src = cb + ((size_t)(q * Kk + code)) * Dd + d0;
    float v[8];
    *(float4*)&v[0] = *(const float4*)src;
    *(float4*)&v[4] = *(const float4*)(src + 4);
    short8 h, l;
    #pragma unroll
    for (int j = 0; j < 8; j++) {
        unsigned short hu = f2bf(v[j]);
        h[j] = (short)hu;
        l[j] = (short)f2bf(v[j] - bf2f(hu));   // exact remainder, then RNE
    }
    char* base = bswz + ((size_t)(q * 64 + t)) * 8192;
    *(short8*)(base + kc * 1024 + ln * 16) = h;
    *(short8*)(base + 4096 + kc * 1024 + ln * 16) = l;
}

// ---------------------------------------------------------------------------
// c2[q][k] = sum_d cb[q][k][d]^2 (exact f32) ; zero commit accumulators.
// (No atomicMax / no memset — cmax is reduced in-kernel, r8-validated.)
// ---------------------------------------------------------------------------
__global__ void k_c2(const float* __restrict__ cb,
                     float* __restrict__ c2,
                     double* __restrict__ commits) {
    int row  = blockIdx.x * 4 + (threadIdx.x >> 6);
    int lane = threadIdx.x & 63;
    const float* p = cb + (size_t)row * Dd;
    float a = p[lane], b = p[lane + 64];
    float s = a * a + b * b;
    #pragma unroll
    for (int off = 32; off; off >>= 1) s += __shfl_down(s, off);
    if (lane == 0) c2[row] = s;
    if (blockIdx.x == 0 && threadIdx.x < NQ) commits[threadIdx.x] = 0.0;
}

// exact f32 chain, d ascending, rlds XOR-swizzled row — numeric order
// identical to the validated version (same fma sequence).
__device__ __forceinline__ float exact_score_sw(const float* __restrict__ rldsb,
                                                int p,
                                                const float* __restrict__ crow,
                                                float c2v) {
    const f32x4* r4 = (const f32x4*)rldsb;
    const f32x4* c4 = (const f32x4*)crow;
    int rb = p * 32, sw = p & 7;
    float a = 0.0f;
    #pragma unroll
    for (int d4 = 0; d4 < 32; d4++) {
        f32x4 r = r4[rb + (d4 ^ sw)];
        f32x4 c = c4[d4];
        a = fmaf(r[0], c[0], a); a = fmaf(r[1], c[1], a);
        a = fmaf(r[2], c[2], a); a = fmaf(r[3], c[3], a);
    }
    return fmaf(-2.0f, a, c2v);
}

// ---------------------------------------------------------------------------
// Fused persistent RVQ — r6 hot loop (446 us, validated; hi/lo 12-MFMA
// screen is load-bearing: A-hi-only variants r5/r8 collapsed via window
// blowup -> contested-path explosion) + validated plumbing:
//  (1) global_load_lds staging (r2-validated): wave w DMAs its 1KB slice
//      of each next tile; no ds_write pass, no staging VGPRs.
//  (2) 4 tiles per barrier (bbuf[2][4], 64KB): halves barrier drains.
//  (3) in-kernel cmax (r8-validated): drops memset+atomicMax (~90us of
//      non-fused overhead r6/r7 carried vs r1).
//  (4) wave-parallel fallback (r8-validated).
// Screening/window/certification numerics byte-identical to r6 (passed):
//   win = 0.05 + 2^(E-12), 2^E >= sb = 2||r||cmax + cmax^2;
//   contested -> exact f32 rescore w/ index tie-break; >=3 -> exact scan.
// ---------------------------------------------------------------------------
__global__ __launch_bounds__(NTHR, 2) void k_rvq_fused(
        float* __restrict__ resid,         // in: initial (B,T,D); out: final
        const float* __restrict__ cb,      // (NQ,K,D) f32
        const char*  __restrict__ bswz,    // (NQ*64 tiles) * 8192 B
        const float* __restrict__ c2g,     // (NQ,K) exact f32
        float* __restrict__ codes_f,       // (NQ,BT)
        double* __restrict__ commits) {    // (NQ)
    __shared__ float rlds[MT * Dd];        // 64 KB, XOR-swizzled f32x4 rows
    __shared__ float c2s[Kk];              // 4 KB
    __shared__ f32x4 bbuf[2][4][512];      // 64 KB [par][tile-in-quad][slice]
    __shared__ float winp[MT];             // per-point rigorous window
    __shared__ float wmax[WV];             // per-wave c2 max partials
    __shared__ float fb1[MT], fb2[MT], fb3[MT];   // packed triples
    __shared__ int   sidxs[MT];
    __shared__ int   nfall, flist[MT];
    __shared__ float csum[WV];

    const int tid  = threadIdx.x;
    const int w    = tid >> 6, ln = tid & 63;
    const int quad = ln >> 4,  m  = ln & 15;
    const int base = blockIdx.x * MT;
    const int prow = w * 16 + m;           // A-frag row owned by this lane

    f32x4* r4 = (f32x4*)rlds;

    // block residual -> swizzled LDS (coalesced, once)
    {
        const f32x4* src = (const f32x4*)(resid + (size_t)base * Dd);
        #pragma unroll
        for (int i = 0; i < (MT * Dd / 4) / NTHR; i++) {    // 8 iters
            int idx = tid + i * NTHR;
            int row = idx >> 5, c4 = idx & 31;
            r4[row * 32 + (c4 ^ (row & 7))] = src[idx];
        }
    }
    // prologue: DMA quad 0 of stage 0 (4 tiles); wave w stages slice w
    {
        const char* srcb = bswz + (size_t)w * 1024 + (size_t)ln * 16;
        char* dstb = (char*)&bbuf[0][0][0] + w * 1024;
        #pragma unroll
        for (int t = 0; t < 4; t++)
            gload_lds16(srcb + t * 8192, dstb + t * 8192);
    }
    int par = 0;
    asm volatile("s_waitcnt vmcnt(0)" ::: "memory");
    __syncthreads();

    #pragma unroll 1
    for (int q = 0; q < NQ; q++) {
        const float* cbq = cb + (size_t)q * Kk * Dd;
        c2s[tid]        = c2g[q * Kk + tid];
        c2s[tid + NTHR] = c2g[q * Kk + tid + NTHR];
        if (tid == 0) nfall = 0;
        __syncthreads();   // c2s ready

        // in-kernel cmax = max_k ||c_k||^2 (block reduce over c2s)
        float lm = fmaxf(c2s[tid], c2s[tid + NTHR]);
        #pragma unroll
        for (int off = 32; off; off >>= 1) lm = fmaxf(lm, __shfl_xor(lm, off));
        if (ln == 0) wmax[w] = lm;
        __syncthreads();
        float cm2 = wmax[0];
        #pragma unroll
        for (int w2 = 1; w2 < WV; w2++) cm2 = fmaxf(cm2, wmax[w2]);
        float cmaxq = sqrtf(cm2);

        // A-fragments (hi+lo) from swizzled rlds; exact ||r||^2 alongside
        short8 Ah[4], Al[4];
        float r2p = 0.0f;
        #pragma unroll
        for (int kc = 0; kc < 4; kc++) {
            int c4a = kc * 8 + quad * 2;
            float v[8];
            *(f32x4*)&v[0] = r4[prow * 32 + (c4a ^ (prow & 7))];
            *(f32x4*)&v[4] = r4[prow * 32 + ((c4a + 1) ^ (prow & 7))];
            short8 h, l;
            #pragma unroll
            for (int j = 0; j < 8; j++) {
                unsigned short hu = f2bf(v[j]);
                h[j] = (short)hu;
                l[j] = (short)f2bf(v[j] - bf2f(hu));
                r2p  = fmaf(v[j], v[j], r2p);
            }
            Ah[kc] = h; Al[kc] = l;
        }
        r2p += __shfl_xor(r2p, 16);
        r2p += __shfl_xor(r2p, 32);            // full ||r||^2 for point prow
        {   // rigorous per-point window: win = 0.05 + 2^(E-12)  (r6 formula)
            float R  = sqrtf(r2p);
            float sb = fmaf(2.0f * R, cmaxq, cmaxq * cmaxq);
            float p2 = exp2f(ceilf(log2f(fmaxf(sb, 2.0f))));
            if (quad == 0) winp[prow] = 0.05f + p2 * (1.0f / 4096.0f);
        }

        // packed top-3 state (4 point-slots per lane)
        float b1[4], b2[4], b3[4];
        #pragma unroll
        for (int j = 0; j < 4; j++) {
            b1[j] = INFINITY; b2[j] = INFINITY; b3[j] = INFINITY;
        }
        __syncthreads();   // winp ready; bbuf[par] holds quad q*16

        #pragma unroll 1
        for (int jq = 0; jq < 16; jq++) {
            const int g = q * 16 + jq;             // global quad index
            if (g + 1 < NQ * 16) {                 // DMA next quad (32 KB)
                const char* srcb = bswz + (size_t)(g + 1) * 32768
                                 + (size_t)w * 1024 + (size_t)ln * 16;
                char* dstb = (char*)&bbuf[par ^ 1][0][0] + w * 1024;
                #pragma unroll
                for (int t = 0; t < 4; t++)
                    gload_lds16(srcb + t * 8192, dstb + t * 8192);
            }
            #pragma unroll
            for (int t = 0; t < 4; t++) {          // four tiles per barrier
                const short8* Bt = (const short8*)&bbuf[par][t][0];
                f32x4 a01 = {0.f, 0.f, 0.f, 0.f};
                f32x4 a23 = {0.f, 0.f, 0.f, 0.f};
                #pragma unroll
                for (int kc = 0; kc < 4; kc++) {
                    short8 ch = Bt[kc * 64 + ln];
                    short8 cl = Bt[256 + kc * 64 + ln];
                    if (kc < 2) {
                        a01 = __builtin_amdgcn_mfma_f32_16x16x32_bf16(Al[kc], ch, a01, 0, 0, 0);
                        a01 = __builtin_amdgcn_mfma_f32_16x16x32_bf16(Ah[kc], cl, a01, 0, 0, 0);
                        a01 = __builtin_amdgcn_mfma_f32_16x16x32_bf16(Ah[kc], ch, a01, 0, 0, 0);
                    } else {
                        a23 = __builtin_amdgcn_mfma_f32_16x16x32_bf16(Al[kc], ch, a23, 0, 0, 0);
                        a23 = __builtin_amdgcn_mfma_f32_16x16x32_bf16(Ah[kc], cl, a23, 0, 0, 0);
                        a23 = __builtin_amdgcn_mfma_f32_16x16x32_bf16(Ah[kc], ch, a23, 0, 0, 0);
                    }
                }
                const int codei = (4 * jq + t) * 16 + m;    // ascending
                const float c2v = c2s[codei];
                const unsigned codeu = (unsigned)codei;
                #pragma unroll
                for (int j = 0; j < 4; j++) {
                    float s = fmaf(-2.0f, a01[j] + a23[j], c2v);
                    float sp = __uint_as_float(
                        (__float_as_uint(s) & 0xFFFFFC00u) | codeu);
                    b3[j] = __builtin_amdgcn_fmed3f(sp, b2[j], b3[j]);
                    b2[j] = __builtin_amdgcn_fmed3f(sp, b1[j], b2[j]);
                    b1[j] = fminf(b1[j], sp);
                }
            }
            asm volatile("s_waitcnt vmcnt(0)" ::: "memory");
            __syncthreads();
            par ^= 1;
        }

        // cross-lane merge of sorted packed triples over the 16 code-cols
        #pragma unroll
        for (int j = 0; j < 4; j++) {
            float v1 = b1[j], v2 = b2[j], v3 = b3[j];
            #pragma unroll
            for (int off = 1; off < 16; off <<= 1) {
                float w1 = __shfl_xor(v1, off);
                float w2 = __shfl_xor(v2, off);
                float w3 = __shfl_xor(v3, off);
                bool aw = v1 < w1;
                float x2 = aw ? v2 : w2, x3 = aw ? v3 : w3;
                float z1 = aw ? w1 : v1, z2 = aw ? w2 : v2;
                v1 = fminf(v1, w1);
                bool s2 = x2 < z1;
                v2 = fminf(x2, z1);
                v3 = s2 ? fminf(x3, z1) : fminf(x2, z2);
            }
            if (m == 0) {
                int p = w * 16 + quad * 4 + j;
                fb1[p] = v1; fb2[p] = v2; fb3[p] = v3;
            }
        }
        __syncthreads();

        // decision + exact rescore of <=2 candidates (thread per point)
        if (tid < MT) {
            int p = tid;
            float v1 = fb1[p], v2 = fb2[p], v3 = fb3[p];
            int   a1 = (int)(__float_as_uint(v1) & 1023u);
            int   a2 = (int)(__float_as_uint(v2) & 1023u);
            float win = winp[p];
            if (v3 <= v1 + win) {
                int sl = atomicAdd(&nfall, 1);     // rare: >=3 in window
                flist[sl] = p;
            } else {
                int bk = a1;
                if (v2 <= v1 + win) {              // two candidates: rescore
                    float s1 = exact_score_sw(rlds, p, cbq + (size_t)a1 * Dd, c2s[a1]);
                    float s2e = exact_score_sw(rlds, p, cbq + (size_t)a2 * Dd, c2s[a2]);
                    if (s2e < s1 || (s2e == s1 && a2 < a1)) bk = a2;
                }
                sidxs[p] = bk;
                codes_f[(size_t)q * BT + base + p] = (float)bk;
            }
        }
        __syncthreads();

        // fallback: WAVE-parallel exact scan (8 points concurrently; rare)
        {
            int nf = nfall;
            for (int fi0 = 0; fi0 < nf; fi0 += WV) {
                int fi = fi0 + w;
                if (fi < nf) {
                    int p = flist[fi];
                    float bv = INFINITY; int bk = 0;
                    #pragma unroll 4
                    for (int c = 0; c < 16; c++) {
                        int k = c * 64 + ln;       // ascending within lane
                        float sc = exact_score_sw(rlds, p,
                                                  cbq + (size_t)k * Dd, c2s[k]);
                        if (sc < bv || (sc == bv && k < bk)) { bv = sc; bk = k; }
                    }
                    #pragma unroll
                    for (int off = 32; off; off >>= 1) {
                        float v2 = __shfl_xor(bv, off);
                        int   k2 = __shfl_xor(bk, off);
                        if (v2 < bv || (v2 == bv && k2 < bk)) { bv = v2; bk = k2; }
                    }
                    if (ln == 0) {
                        sidxs[p] = bk;
                        codes_f[(size_t)q * BT + base + p] = (float)bk;
                    }
                }
            }
        }
        __syncthreads();

        // fused STE update (swizzled rlds): thread -> point tid>>2,
        // dims [(tid&3)*32, +32). Per-element op order bit-identical.
        {
            int p = tid >> 2;
            int rb = p * 32, sw = p & 7, cb4 = (tid & 3) * 8;
            const float* qrow = cbq + ((size_t)sidxs[p]) * Dd + (tid & 3) * 32;
            float cacc = 0.0f;
            #pragma unroll
            for (int hh = 0; hh < 8; hh++) {
                f32x4 r  = r4[rb + ((cb4 + hh) ^ sw)];
                f32x4 qv = *(const f32x4*)(qrow + hh * 4);
                float t1x = qv[0] - r[0], t1y = qv[1] - r[1];
                float t1z = qv[2] - r[2], t1w = qv[3] - r[3];  // q - residual
                float qsx = r[0] + t1x, qsy = r[1] + t1y;
                float qsz = r[2] + t1z, qsw = r[3] + t1w;      // straight-through
                f32x4 nr = { r[0] - qsx, r[1] - qsy, r[2] - qsz, r[3] - qsw };
                r4[rb + ((cb4 + hh) ^ sw)] = nr;
                cacc = fmaf(t1x, t1x, cacc); cacc = fmaf(t1y, t1y, cacc);
                cacc = fmaf(t1z, t1z, cacc); cacc = fmaf(t1w, t1w, cacc);
            }
            #pragma unroll
            for (int off = 32; off; off >>= 1) cacc += __shfl_down(cacc, off);
            if (ln == 0) csum[w] = cacc;
        }
        __syncthreads();
        if (tid == 0) {
            double sd = 0.0;
            #pragma unroll
            for (int w2 = 0; w2 < WV; w2++) sd += (double)csum[w2];
            atomicAdd(commits + q, sd);
        }
        __syncthreads();   // gates next stage's c2s overwrite + A-prep
    }

    // final residual back to global (coalesced, once)
    {
        f32x4* dst = (f32x4*)(resid + (size_t)base * Dd);
        #pragma unroll
        for (int i = 0; i < (MT * Dd / 4) / NTHR; i++) {
            int idx = tid + i * NTHR;
            int row = idx >> 5, c4 = idx & 31;
            dst[idx] = r4[row * 32 + (c4 ^ (row & 7))];
        }
    }
}

// ---------------------------------------------------------------------------
// final: out(B,D,T) = x - resid_final^T
// ---------------------------------------------------------------------------
__global__ void k_final(const float* __restrict__ x,
                        const float* __restrict__ resid,
                        float* __restrict__ outq) {
    __shared__ float tile[32][33];
    int b  = blockIdx.z;
    int t0 = blockIdx.x * 32, d0 = blockIdx.y * 32;
    int tx = threadIdx.x, ty = threadIdx.y;   // 32 x 8
    #pragma unroll
    for (int k = 0; k < 4; k++) {
        int t = t0 + ty + k * 8;
        tile[ty + k * 8][tx] = resid[((size_t)(b * Tt + t)) * Dd + d0 + tx];
    }
    __syncthreads();
    #pragma unroll
    for (int k = 0; k < 4; k++) {
        int d = d0 + ty + k * 8;
        size_t o = ((size_t)(b * Dd + d)) * Tt + t0 + tx;
        outq[o] = x[o] - tile[tx][ty + k * 8];
    }
}

// ---------------------------------------------------------------------------
// scalars: bw = n_q * log2(K) * frame_rate ; penalty = mean(commits)
// ---------------------------------------------------------------------------
__global__ void k_scalars(const double* __restrict__ commits,
                          const int* __restrict__ frame_rate,
                          float* __restrict__ outs) {
    if (threadIdx.x == 0 && blockIdx.x == 0) {
        double s = 0.0;
        #pragma unroll
        for (int q = 0; q < NQ; q++) s += commits[q];
        double per_elem = s / ((double)NQ * (double)BT * (double)Dd);
        outs[0] = (float)(NQ * 10.0 * (double)frame_rate[0]); // log2(1024)=10
        outs[1] = (float)per_elem;
    }
}

extern "C" void kernel_launch(void* const* d_in, const int* in_sizes, int n_in,
                              void* d_out, int out_size, void* d_ws, size_t ws_size,
                              hipStream_t stream) {
    const float* x  = (const float*)d_in[0];   // (B, D, T)
    const float* cb = (const float*)d_in[1];   // (NQ, K, D)
    const int*   fr = (const int*)d_in[2];     // frame_rate

    float* outq    = (float*)d_out;                       // (B,D,T) 4194304
    float* codes_f = outq + (size_t)Bsz * Dd * Tt;        // (NQ,B,T) 262144
    float* scal    = codes_f + (size_t)NQ * BT;           // bw, penalty

    char* ws = (char*)d_ws;
    float*    resid   = (float*)ws;                            // BT*D f32
    float*    c2      = resid + (size_t)BT * Dd;               // NQ*K f32
    double*   commits = (double*)(c2 + (size_t)NQ * Kk);       // NQ f64
    size_t    off     = (size_t)((char*)(commits + NQ) - ws);
    char*     bswz    = ws + ((off + 255) & ~(size_t)255);     // 256B aligned

    dim3 tb(32, 8, 1);
    k_init<<<dim3(Tt / 32, Dd / 32, Bsz), tb, 0, stream>>>(x, resid);
    k_prep<<<NQ * 256, 64, 0, stream>>>(cb, bswz);
    k_c2<<<NQ * Kk / 4, 256, 0, stream>>>(cb, c2, commits);

    k_rvq_fused<<<BT / MT, NTHR, 0, stream>>>(resid, cb, bswz, c2,
                                              codes_f, commits);

    k_final<<<dim3(Tt / 32, Dd / 32, Bsz), tb, 0, stream>>>(x, resid, outq);
    k_scalars<<<1, 64, 0, stream>>>(commits, fr, scal);
}